// Round 1
// 3408.795 us; speedup vs baseline: 1.1481x; 1.1481x over previous
//
#include <hip/hip_runtime.h>
#include <math.h>

#define N_ 32
#define S_ 197
#define D_ 768
#define H_ 12
#define L_ 8
#define FF_ 3072
#define MTOK (N_ * S_)      // 6304
#define ND (N_ * S_ * D_)   // 4841472

typedef __attribute__((ext_vector_type(8))) short short8x;
typedef __attribute__((ext_vector_type(4))) float floatx4;
typedef unsigned short ushort_t;
typedef unsigned int uint_t;

__device__ __forceinline__ ushort_t f2bf_rn(float x) {
  uint_t u = __float_as_uint(x);
  uint_t r = (u + 0x7fff + ((u >> 16) & 1)) >> 16;
  return (ushort_t)r;
}
__device__ __forceinline__ float bf2f(ushort_t h) {
  return __uint_as_float(((uint_t)h) << 16);
}

// async global->LDS, 16B per lane, dest = wave-uniform base + lane*16
__device__ __forceinline__ void gload16(const ushort_t* g, ushort_t* l) {
  __builtin_amdgcn_global_load_lds((const __attribute__((address_space(1))) void*)g,
                                   (__attribute__((address_space(3))) void*)l, 16, 0, 0);
}

// ---------------- patchify ----------------
__global__ __launch_bounds__(256) void patchify_kernel(const float* __restrict__ img,
                                                       ushort_t* __restrict__ phi,
                                                       ushort_t* __restrict__ plo) {
  int idx = blockIdx.x * 256 + threadIdx.x;
  if (idx >= 6272 * 768) return;
  int mp = idx / 768, kk = idx - mp * 768;
  int n = mp / 196, p = mp - n * 196;
  int py = p / 14, px = p - py * 14;
  int c = kk >> 8, r = kk & 255;
  int u = r >> 4, vv = r & 15;
  float val = img[((size_t)(n * 3 + c) * 224 + py * 16 + u) * 224 + px * 16 + vv];
  ushort_t hi = f2bf_rn(val);
  phi[idx] = hi;
  plo[idx] = f2bf_rn(val - bf2f(hi));
}

__global__ __launch_bounds__(256) void cls_init_kernel(const float* __restrict__ cls_tok,
                                                       const float* __restrict__ pos,
                                                       float* __restrict__ x) {
  int idx = blockIdx.x * 256 + threadIdx.x;  // 32*768
  int n = idx / 768, d = idx - n * 768;
  x[(size_t)n * S_ * D_ + d] = cls_tok[d] + pos[d];
}

// ---------------- weight transpose + hi/lo split ----------------
__global__ __launch_bounds__(256) void wconvert_kernel(const float* __restrict__ W,
                                                       ushort_t* __restrict__ Thi,
                                                       ushort_t* __restrict__ Tlo, int K, int N) {
  __shared__ float T[32][36];
  int n0 = blockIdx.x * 32, k0 = blockIdx.y * 32;
  int t = threadIdx.x;
  int r = t >> 3, c4 = (t & 7) * 4;
  float4 v = *(const float4*)&W[(size_t)(k0 + r) * N + n0 + c4];
  T[c4 + 0][r] = v.x;
  T[c4 + 1][r] = v.y;
  T[c4 + 2][r] = v.z;
  T[c4 + 3][r] = v.w;
  __syncthreads();
  ushort4 hi, lo;
  float a;
  a = T[r][c4 + 0]; hi.x = f2bf_rn(a); lo.x = f2bf_rn(a - bf2f(hi.x));
  a = T[r][c4 + 1]; hi.y = f2bf_rn(a); lo.y = f2bf_rn(a - bf2f(hi.y));
  a = T[r][c4 + 2]; hi.z = f2bf_rn(a); lo.z = f2bf_rn(a - bf2f(hi.z));
  a = T[r][c4 + 3]; hi.w = f2bf_rn(a); lo.w = f2bf_rn(a - bf2f(hi.w));
  size_t o = (size_t)(n0 + r) * K + k0 + c4;
  *(ushort4*)&Thi[o] = hi;
  *(ushort4*)&Tlo[o] = lo;
}

// ---------------- split-bf16 MFMA GEMM --------------
// grid: (mblocks, nblocks, KP). m-fastest for B-slab L2 reuse.
// Staging: global_load_lds (16B/lane), linear LDS rows of 32 ushorts (64B).
// Source-side chunk swizzle c ^= (row>>1)&3 (16B chunks), same XOR on ds_read
// addresses -> conflict-free b128 reads without padding (rule 21 / m173).
// EPI_ATOM (KP=2): both K-halves unsafeAtomicAdd into Cf (z==0 adds bias).
#define EPI_PATCH 1
#define EPI_GELU 2
#define EPI_ATOM 3

template <int EPI, int KP>
__global__ __launch_bounds__(256) void gemm_mfma(
    const ushort_t* __restrict__ Ahi, const ushort_t* __restrict__ Alo,
    const ushort_t* __restrict__ Bhi, const ushort_t* __restrict__ Blo,
    const float* __restrict__ bias, float* __restrict__ Cf, ushort_t* __restrict__ Chi,
    ushort_t* __restrict__ Clo, int M, int K, int Nc, const float* __restrict__ pos) {
  __shared__ ushort_t As[2][128 * 32];   // hi/lo planes, 8KB each
  __shared__ ushort_t Bs[2][128 * 32];
  int tid = threadIdx.x;
  int wave = tid >> 6, lane = tid & 63;
  int wr = (wave >> 1) * 64, wc = (wave & 1) * 64;
  int q = lane >> 4, l15 = lane & 15;
  int m0 = blockIdx.x * 128, n0 = blockIdx.y * 128;
  int kbeg = (KP > 1) ? blockIdx.z * (K / KP) : 0;
  int kend = kbeg + K / KP;

  floatx4 acc[4][4];
#pragma unroll
  for (int i = 0; i < 4; ++i)
#pragma unroll
    for (int j = 0; j < 4; ++j)
#pragma unroll
      for (int e = 0; e < 4; ++e) acc[i][j][e] = 0.f;

  // staging geometry: wave stages rows [wave*32, wave*32+32), 16 rows/instr
  int srow_in = lane >> 2;                 // 0..15 within instr
  int schunk = lane & 3;                   // 16B chunk within row
  // fragment read swizzle (row bits 1-2 come from l15 only)
  int csw = (q ^ ((l15 >> 1) & 3)) * 8;

  for (int k0 = kbeg; k0 < kend; k0 += 32) {
#pragma unroll
    for (int j = 0; j < 2; ++j) {
      int rbase = (wave << 5) + (j << 4);
      int r = rbase + srow_in;
      int cc = schunk ^ ((r >> 1) & 3);    // pre-swizzled source chunk
      int gm = m0 + r;
      if (gm > M - 1) gm = M - 1;
      size_t aoff = (size_t)gm * K + k0 + cc * 8;
      size_t boff = (size_t)(n0 + r) * K + k0 + cc * 8;
      gload16(&Ahi[aoff], &As[0][rbase * 32]);
      gload16(&Alo[aoff], &As[1][rbase * 32]);
      gload16(&Bhi[boff], &Bs[0][rbase * 32]);
      gload16(&Blo[boff], &Bs[1][rbase * 32]);
    }
    asm volatile("s_waitcnt vmcnt(0)" ::: "memory");
    __syncthreads();

    short8x ah[4], al[4], bh[4], bl[4];
#pragma unroll
    for (int i = 0; i < 4; ++i) {
      int ao = (wr + i * 16 + l15) * 32 + csw;
      int bo = (wc + i * 16 + l15) * 32 + csw;
      ah[i] = *(const short8x*)&As[0][ao];
      al[i] = *(const short8x*)&As[1][ao];
      bh[i] = *(const short8x*)&Bs[0][bo];
      bl[i] = *(const short8x*)&Bs[1][bo];
    }
#pragma unroll
    for (int i = 0; i < 4; ++i)
#pragma unroll
      for (int j = 0; j < 4; ++j) {
        acc[i][j] = __builtin_amdgcn_mfma_f32_16x16x32_bf16(ah[i], bh[j], acc[i][j], 0, 0, 0);
        acc[i][j] = __builtin_amdgcn_mfma_f32_16x16x32_bf16(ah[i], bl[j], acc[i][j], 0, 0, 0);
        acc[i][j] = __builtin_amdgcn_mfma_f32_16x16x32_bf16(al[i], bh[j], acc[i][j], 0, 0, 0);
      }
    __syncthreads();
  }

#pragma unroll
  for (int i = 0; i < 4; ++i) {
#pragma unroll
    for (int j = 0; j < 4; ++j) {
      int col = n0 + wc + j * 16 + l15;
#pragma unroll
      for (int r4 = 0; r4 < 4; ++r4) {
        int gr = m0 + wr + i * 16 + q * 4 + r4;
        if (gr >= M) continue;
        if (EPI == EPI_ATOM) {
          float v = acc[i][j][r4];
          if (KP == 1 || blockIdx.z == 0) v += bias[col];
          unsafeAtomicAdd(&Cf[(size_t)gr * 768 + col], v);
        } else {
          float v = acc[i][j][r4] + bias[col];
          if (EPI == EPI_PATCH) {
            int n = gr / 196, t = gr - n * 196 + 1;
            Cf[((size_t)n * S_ + t) * 768 + col] = v + pos[(size_t)t * 768 + col];
          } else {  // EPI_GELU
            float g = 0.5f * v * (1.f + erff(v * 0.70710678118654752f));
            ushort_t hi = f2bf_rn(g);
            size_t o = (size_t)gr * FF_ + col;
            Chi[o] = hi;
            Clo[o] = f2bf_rn(g - bf2f(hi));
          }
        }
      }
    }
  }
}

// ---------------- LayerNorm -> bf16 hi/lo ----------------
__global__ __launch_bounds__(256) void ln_kernel(const float* __restrict__ x,
                                                 ushort_t* __restrict__ hhi,
                                                 ushort_t* __restrict__ hlo,
                                                 const float* __restrict__ w,
                                                 const float* __restrict__ b) {
  int tok = blockIdx.x * 4 + (threadIdx.x >> 6);
  int lane = threadIdx.x & 63;
  const float* xr = x + (size_t)tok * 768;
  float4 v[3];
  float s = 0.f, s2 = 0.f;
#pragma unroll
  for (int i = 0; i < 3; ++i) {
    v[i] = *(const float4*)&xr[i * 256 + lane * 4];
    s += v[i].x + v[i].y + v[i].z + v[i].w;
    s2 += v[i].x * v[i].x + v[i].y * v[i].y + v[i].z * v[i].z + v[i].w * v[i].w;
  }
#pragma unroll
  for (int m = 32; m > 0; m >>= 1) { s += __shfl_xor(s, m, 64); s2 += __shfl_xor(s2, m, 64); }
  float mu = s * (1.f / 768.f);
  float var = s2 * (1.f / 768.f) - mu * mu;
  float rs = rsqrtf(var + 1e-5f);
#pragma unroll
  for (int i = 0; i < 3; ++i) {
    float4 wv = *(const float4*)&w[i * 256 + lane * 4];
    float4 bv = *(const float4*)&b[i * 256 + lane * 4];
    float o0 = (v[i].x - mu) * rs * wv.x + bv.x;
    float o1 = (v[i].y - mu) * rs * wv.y + bv.y;
    float o2 = (v[i].z - mu) * rs * wv.z + bv.z;
    float o3 = (v[i].w - mu) * rs * wv.w + bv.w;
    ushort4 oh, ol;
    oh.x = f2bf_rn(o0); ol.x = f2bf_rn(o0 - bf2f(oh.x));
    oh.y = f2bf_rn(o1); ol.y = f2bf_rn(o1 - bf2f(oh.y));
    oh.z = f2bf_rn(o2); ol.z = f2bf_rn(o2 - bf2f(oh.z));
    oh.w = f2bf_rn(o3); ol.w = f2bf_rn(o3 - bf2f(oh.w));
    size_t o = (size_t)tok * 768 + i * 256 + lane * 4;
    *(ushort4*)&hhi[o] = oh;
    *(ushort4*)&hlo[o] = ol;
  }
}

// ---------------- QKV projection via MFMA: block = 128 tokens x head ----------------
#define KSTR 72

__global__ __launch_bounds__(256) void qkv_mfma(
    const ushort_t* __restrict__ hhi, const ushort_t* __restrict__ hlo,
    const float* __restrict__ Wq, const float* __restrict__ Wk, const float* __restrict__ Wv,
    const float* __restrict__ bq, const float* __restrict__ bk, const float* __restrict__ bv,
    ushort_t* __restrict__ qhi, ushort_t* __restrict__ qlo, ushort_t* __restrict__ khi,
    ushort_t* __restrict__ klo, ushort_t* __restrict__ vhi, ushort_t* __restrict__ vlo) {
  __shared__ ushort_t As[2][128 * KSTR];
  __shared__ ushort_t Ws[2][64 * KSTR];
  int tid = threadIdx.x;
  int wave = tid >> 6, lane = tid & 63;
  int q = lane >> 4, l15 = lane & 15;
  int m0 = blockIdx.x * 128, h = blockIdx.y;
  int wm = wave >> 1, wj = wave & 1;

#pragma unroll
  for (int p = 0; p < 2; ++p) {
    const ushort_t* src = p == 0 ? hhi : hlo;
#pragma unroll
    for (int it = 0; it < 4; ++it) {
      int idx = it * 256 + tid;
      int r = idx >> 3, c = idx & 7;
      int gm = m0 + r;
      if (gm > MTOK - 1) gm = MTOK - 1;
      *(uint4*)&As[p][r * KSTR + c * 8] = *(const uint4*)&src[(size_t)gm * 768 + h * 64 + c * 8];
    }
  }

  const float* Wmat[3] = {Wq + (size_t)h * 4096, Wk + (size_t)h * 4096, Wv + (size_t)h * 4096};
  const float* Bmat[3] = {bq + h * 64, bk + h * 64, bv + h * 64};
  ushort_t* Ohi[3] = {qhi, khi, vhi};
  ushort_t* Olo[3] = {qlo, klo, vlo};

  for (int mat = 0; mat < 3; ++mat) {
    __syncthreads();
#pragma unroll
    for (int it = 0; it < 4; ++it) {
      int idx = it * 256 + tid;
      int r = idx >> 4, c4 = (idx & 15) * 4;
      float4 wv = *(const float4*)&Wmat[mat][r * 64 + c4];
      float vals[4] = {wv.x, wv.y, wv.z, wv.w};
#pragma unroll
      for (int i = 0; i < 4; ++i) {
        ushort_t hi = f2bf_rn(vals[i]);
        Ws[0][(c4 + i) * KSTR + r] = hi;
        Ws[1][(c4 + i) * KSTR + r] = f2bf_rn(vals[i] - bf2f(hi));
      }
    }
    __syncthreads();

    floatx4 acc[4][2];
#pragma unroll
    for (int i = 0; i < 4; ++i)
#pragma unroll
      for (int j = 0; j < 2; ++j)
#pragma unroll
        for (int e = 0; e < 4; ++e) acc[i][j][e] = 0.f;

#pragma unroll
    for (int ks = 0; ks < 2; ++ks) {
      short8x bh[2], bl[2];
#pragma unroll
      for (int j = 0; j < 2; ++j) {
        int bb = (wj * 32 + j * 16 + l15) * KSTR + ks * 32 + q * 8;
        bh[j] = *(const short8x*)&Ws[0][bb];
        bl[j] = *(const short8x*)&Ws[1][bb];
      }
#pragma unroll
      for (int i = 0; i < 4; ++i) {
        int ab = (wm * 64 + i * 16 + l15) * KSTR + ks * 32 + q * 8;
        short8x ah = *(const short8x*)&As[0][ab];
        short8x al = *(const short8x*)&As[1][ab];
#pragma unroll
        for (int j = 0; j < 2; ++j) {
          acc[i][j] = __builtin_amdgcn_mfma_f32_16x16x32_bf16(ah, bh[j], acc[i][j], 0, 0, 0);
          acc[i][j] = __builtin_amdgcn_mfma_f32_16x16x32_bf16(ah, bl[j], acc[i][j], 0, 0, 0);
          acc[i][j] = __builtin_amdgcn_mfma_f32_16x16x32_bf16(al, bh[j], acc[i][j], 0, 0, 0);
        }
      }
    }
#pragma unroll
    for (int i = 0; i < 4; ++i)
#pragma unroll
      for (int j = 0; j < 2; ++j) {
        int col = wj * 32 + j * 16 + l15;
        float bias = Bmat[mat][col];
#pragma unroll
        for (int r = 0; r < 4; ++r) {
          int tok = m0 + wm * 64 + i * 16 + q * 4 + r;
          if (tok >= MTOK) continue;
          float v = acc[i][j][r] + bias;
          ushort_t hi = f2bf_rn(v);
          size_t o = (size_t)tok * 768 + h * 64 + col;
          Ohi[mat][o] = hi;
          Olo[mat][o] = f2bf_rn(v - bf2f(hi));
        }
      }
  }
}

// ---------------- MFMA flash attention ----------------
__global__ __launch_bounds__(256) void attn_mfma(
    const ushort_t* __restrict__ qhi, const ushort_t* __restrict__ qlo,
    const ushort_t* __restrict__ khi, const ushort_t* __restrict__ klo,
    const ushort_t* __restrict__ vhi, const ushort_t* __restrict__ vlo,
    float* __restrict__ X) {
  __shared__ ushort_t Qs[2][64 * KSTR];
  __shared__ ushort_t Ks[2][64 * KSTR];
  __shared__ ushort_t Vs[2][64 * KSTR];
  int tid = threadIdx.x;
  int wave = tid >> 6, lane = tid & 63;
  int q = lane >> 4, l15 = lane & 15;
  int qc = blockIdx.x, h = blockIdx.y, n = blockIdx.z;
  int q0 = qc * 64;
  int row0 = wave * 16;

#pragma unroll
  for (int p = 0; p < 2; ++p) {
    const ushort_t* src = p == 0 ? qhi : qlo;
#pragma unroll
    for (int it = 0; it < 2; ++it) {
      int idx = it * 256 + tid;
      int r = idx >> 3, c = idx & 7;
      int gr = q0 + r;
      if (gr > S_ - 1) gr = S_ - 1;
      *(uint4*)&Qs[p][r * KSTR + c * 8] =
          *(const uint4*)&src[((size_t)n * S_ + gr) * 768 + h * 64 + c * 8];
    }
  }
  __syncthreads();
  short8x qa_h[2], qa_l[2];
#pragma unroll
  for (int ks = 0; ks < 2; ++ks) {
    int ab = (row0 + l15) * KSTR + ks * 32 + q * 8;
    qa_h[ks] = *(const short8x*)&Qs[0][ab];
    qa_l[ks] = *(const short8x*)&Qs[1][ab];
  }

  float mrow[4], lrow[4];
  floatx4 oa[4];
#pragma unroll
  for (int r = 0; r < 4; ++r) { mrow[r] = -INFINITY; lrow[r] = 0.f; }
#pragma unroll
  for (int j = 0; j < 4; ++j)
#pragma unroll
    for (int e = 0; e < 4; ++e) oa[j][e] = 0.f;

  for (int t = 0; t < 4; ++t) {
    __syncthreads();
#pragma unroll
    for (int p = 0; p < 2; ++p) {
      const ushort_t* src = p == 0 ? khi : klo;
#pragma unroll
      for (int it = 0; it < 2; ++it) {
        int idx = it * 256 + tid;
        int r = idx >> 3, c = idx & 7;
        int gk = t * 64 + r;
        if (gk > S_ - 1) gk = S_ - 1;
        *(uint4*)&Ks[p][r * KSTR + c * 8] =
            *(const uint4*)&src[((size_t)n * S_ + gk) * 768 + h * 64 + c * 8];
      }
    }
    {
      int d = tid & 63, kg = tid >> 6;
#pragma unroll
      for (int p = 0; p < 2; ++p) {
        const ushort_t* src = p == 0 ? vhi : vlo;
#pragma unroll
        for (int k4 = 0; k4 < 4; ++k4) {
          ushort4 pk;
          ushort_t tmp[4];
#pragma unroll
          for (int i = 0; i < 4; ++i) {
            int gk = t * 64 + kg * 16 + k4 * 4 + i;
            if (gk > S_ - 1) gk = S_ - 1;
            tmp[i] = src[((size_t)n * S_ + gk) * 768 + h * 64 + d];
          }
          pk.x = tmp[0]; pk.y = tmp[1]; pk.z = tmp[2]; pk.w = tmp[3];
          *(ushort4*)&Vs[p][d * KSTR + kg * 16 + k4 * 4] = pk;
        }
      }
    }
    __syncthreads();

    floatx4 sc[4];
#pragma unroll
    for (int j = 0; j < 4; ++j) {
#pragma unroll
      for (int e = 0; e < 4; ++e) sc[j][e] = 0.f;
#pragma unroll
      for (int ks = 0; ks < 2; ++ks) {
        int bb = (j * 16 + l15) * KSTR + ks * 32 + q * 8;
        short8x kb_h = *(const short8x*)&Ks[0][bb];
        short8x kb_l = *(const short8x*)&Ks[1][bb];
        sc[j] = __builtin_amdgcn_mfma_f32_16x16x32_bf16(qa_h[ks], kb_h, sc[j], 0, 0, 0);
        sc[j] = __builtin_amdgcn_mfma_f32_16x16x32_bf16(qa_h[ks], kb_l, sc[j], 0, 0, 0);
        sc[j] = __builtin_amdgcn_mfma_f32_16x16x32_bf16(qa_l[ks], kb_h, sc[j], 0, 0, 0);
      }
    }
    __syncthreads();

    bool kvalid[4];
#pragma unroll
    for (int j = 0; j < 4; ++j) kvalid[j] = (t * 64 + j * 16 + l15) < S_;
#pragma unroll
    for (int r = 0; r < 4; ++r) {
      float sv[4];
#pragma unroll
      for (int j = 0; j < 4; ++j) sv[j] = kvalid[j] ? sc[j][r] * 0.125f : -INFINITY;
      float mx = fmaxf(fmaxf(sv[0], sv[1]), fmaxf(sv[2], sv[3]));
#pragma unroll
      for (int msk = 1; msk < 16; msk <<= 1) mx = fmaxf(mx, __shfl_xor(mx, msk, 64));
      float mn = fmaxf(mrow[r], mx);
      float al = expf(mrow[r] - mn);
      float p[4], ps = 0.f;
#pragma unroll
      for (int j = 0; j < 4; ++j) { p[j] = expf(sv[j] - mn); ps += p[j]; }
#pragma unroll
      for (int msk = 1; msk < 16; msk <<= 1) ps += __shfl_xor(ps, msk, 64);
      lrow[r] = lrow[r] * al + ps;
      mrow[r] = mn;
#pragma unroll
      for (int j = 0; j < 4; ++j) oa[j][r] *= al;
      int prow = (row0 + q * 4 + r) * KSTR;
#pragma unroll
      for (int j = 0; j < 4; ++j) {
        ushort_t phv = f2bf_rn(p[j]);
        Ks[0][prow + j * 16 + l15] = phv;
        Ks[1][prow + j * 16 + l15] = f2bf_rn(p[j] - bf2f(phv));
      }
    }

#pragma unroll
    for (int ks = 0; ks < 2; ++ks) {
      int ab = (row0 + l15) * KSTR + ks * 32 + q * 8;
      short8x pa_h = *(const short8x*)&Ks[0][ab];
      short8x pa_l = *(const short8x*)&Ks[1][ab];
#pragma unroll
      for (int j = 0; j < 4; ++j) {
        int bb = (j * 16 + l15) * KSTR + ks * 32 + q * 8;
        short8x vb_h = *(const short8x*)&Vs[0][bb];
        short8x vb_l = *(const short8x*)&Vs[1][bb];
        oa[j] = __builtin_amdgcn_mfma_f32_16x16x32_bf16(pa_h, vb_h, oa[j], 0, 0, 0);
        oa[j] = __builtin_amdgcn_mfma_f32_16x16x32_bf16(pa_h, vb_l, oa[j], 0, 0, 0);
        oa[j] = __builtin_amdgcn_mfma_f32_16x16x32_bf16(pa_l, vb_h, oa[j], 0, 0, 0);
      }
    }
  }

#pragma unroll
  for (int r = 0; r < 4; ++r) {
    int row = q0 + row0 + q * 4 + r;
    if (row >= S_) continue;
    float invl = 1.f / lrow[r];
#pragma unroll
    for (int j = 0; j < 4; ++j)
      X[((size_t)n * S_ + row) * 768 + h * 64 + j * 16 + l15] += oa[j][r] * invl;
  }
}

// ---------------- classifier head + softmax ----------------
__global__ __launch_bounds__(256) void head_kernel(const float* __restrict__ x,
                                                   const float* __restrict__ Wout,
                                                   const float* __restrict__ bout,
                                                   float* __restrict__ out) {
  __shared__ float cls[768];
  __shared__ float red[4];
  int n = blockIdx.x, tid = threadIdx.x;
  int w = tid >> 6, lane = tid & 63;
  for (int d = tid; d < 768; d += 256) cls[d] = x[(size_t)n * S_ * D_ + d];
  __syncthreads();
  int j0 = tid * 4;
  bool act = j0 < 1000;
  float a0 = 0.f, a1 = 0.f, a2 = 0.f, a3 = 0.f;
  if (act) {
    for (int kk = 0; kk < 768; ++kk) {
      float c = cls[kk];
      float4 wv = *(const float4*)&Wout[(size_t)kk * 1000 + j0];
      a0 += c * wv.x;
      a1 += c * wv.y;
      a2 += c * wv.z;
      a3 += c * wv.w;
    }
    a0 += bout[j0];
    a1 += bout[j0 + 1];
    a2 += bout[j0 + 2];
    a3 += bout[j0 + 3];
  }
  float mx = act ? fmaxf(fmaxf(a0, a1), fmaxf(a2, a3)) : -INFINITY;
#pragma unroll
  for (int m = 32; m > 0; m >>= 1) mx = fmaxf(mx, __shfl_xor(mx, m, 64));
  if (lane == 0) red[w] = mx;
  __syncthreads();
  mx = fmaxf(fmaxf(red[0], red[1]), fmaxf(red[2], red[3]));
  __syncthreads();
  float e0 = 0.f, e1 = 0.f, e2 = 0.f, e3 = 0.f, ss = 0.f;
  if (act) {
    e0 = expf(a0 - mx);
    e1 = expf(a1 - mx);
    e2 = expf(a2 - mx);
    e3 = expf(a3 - mx);
    ss = e0 + e1 + e2 + e3;
  }
#pragma unroll
  for (int m = 32; m > 0; m >>= 1) ss += __shfl_xor(ss, m, 64);
  if (lane == 0) red[w] = ss;
  __syncthreads();
  ss = red[0] + red[1] + red[2] + red[3];
  if (act) {
    float inv = 1.f / ss;
    out[(size_t)n * 1000 + j0] = e0 * inv;
    out[(size_t)n * 1000 + j0 + 1] = e1 * inv;
    out[(size_t)n * 1000 + j0 + 2] = e2 * inv;
    out[(size_t)n * 1000 + j0 + 3] = e3 * inv;
  }
}

extern "C" void kernel_launch(void* const* d_in, const int* in_sizes, int n_in, void* d_out,
                              int out_size, void* d_ws, size_t ws_size, hipStream_t stream) {
  const float* images = (const float*)d_in[0];
  const float* Wm = (const float*)d_in[1];
  const float* bm = (const float*)d_in[2];
  const float* cls_tok = (const float*)d_in[3];
  const float* pos_emb = (const float*)d_in[4];
  const float* ln1_w = (const float*)d_in[5];
  const float* ln1_b = (const float*)d_in[6];
  const float* Wq = (const float*)d_in[7];
  const float* bq = (const float*)d_in[8];
  const float* Wk = (const float*)d_in[9];
  const float* bk = (const float*)d_in[10];
  const float* Wv = (const float*)d_in[11];
  const float* bv = (const float*)d_in[12];
  const float* ln2_w = (const float*)d_in[13];
  const float* ln2_b = (const float*)d_in[14];
  const float* W1 = (const float*)d_in[15];
  const float* b1 = (const float*)d_in[16];
  const float* W2 = (const float*)d_in[17];
  const float* b2 = (const float*)d_in[18];
  const float* Wout = (const float*)d_in[19];
  const float* bout = (const float*)d_in[20];
  float* out = (float*)d_out;

  // --- workspace map (identical layout) ---
  char* base = (char*)d_ws;
  float* x = (float*)base;
  ushort_t* hhi = (ushort_t*)(base + (size_t)ND * 4);
  ushort_t* hlo = hhi + (size_t)ND;
  char* R = base + (size_t)ND * 8;
  ushort_t* qhi = (ushort_t*)R;
  ushort_t* qlo = qhi + (size_t)ND;
  ushort_t* khi = qlo + (size_t)ND;
  ushort_t* klo = khi + (size_t)ND;
  ushort_t* vhi = klo + (size_t)ND;
  ushort_t* vlo = vhi + (size_t)ND;
  ushort_t* ghi = (ushort_t*)R;
  ushort_t* glo = ghi + (size_t)MTOK * FF_;
  ushort_t* phi = (ushort_t*)R;
  ushort_t* plo = phi + (size_t)6272 * 768;
  char* WB = R + (size_t)MTOK * FF_ * 4;
  ushort_t* w1hi = (ushort_t*)WB;
  ushort_t* w1lo = w1hi + (size_t)768 * FF_;
  ushort_t* w2hi = w1lo + (size_t)768 * FF_;
  ushort_t* w2lo = w2hi + (size_t)768 * FF_;

  patchify_kernel<<<(6272 * 768 + 255) / 256, 256, 0, stream>>>(images, phi, plo);
  wconvert_kernel<<<dim3(24, 24), 256, 0, stream>>>(Wm, w1hi, w1lo, 768, 768);
  gemm_mfma<EPI_PATCH, 1><<<dim3(49, 6), 256, 0, stream>>>(phi, plo, w1hi, w1lo, bm, x,
                                                           nullptr, nullptr, 6272, 768, 768,
                                                           pos_emb);
  cls_init_kernel<<<(32 * 768) / 256, 256, 0, stream>>>(cls_tok, pos_emb, x);

  for (int l = 0; l < 8; ++l) {
    ln_kernel<<<MTOK / 4, 256, 0, stream>>>(x, hhi, hlo, ln1_w + l * 768, ln1_b + l * 768);
    qkv_mfma<<<dim3(50, 12), 256, 0, stream>>>(
        hhi, hlo, Wq + (size_t)l * 49152, Wk + (size_t)l * 49152, Wv + (size_t)l * 49152,
        bq + l * 768, bk + l * 768, bv + l * 768, qhi, qlo, khi, klo, vhi, vlo);
    attn_mfma<<<dim3(4, 12, 32), 256, 0, stream>>>(qhi, qlo, khi, klo, vhi, vlo, x);
    ln_kernel<<<MTOK / 4, 256, 0, stream>>>(x, hhi, hlo, ln2_w + l * 768, ln2_b + l * 768);
    wconvert_kernel<<<dim3(96, 24), 256, 0, stream>>>(W1 + (size_t)l * 768 * FF_, w1hi, w1lo,
                                                      768, FF_);
    gemm_mfma<EPI_GELU, 1><<<dim3(50, 24), 256, 0, stream>>>(hhi, hlo, w1hi, w1lo, b1 + l * FF_,
                                                             nullptr, ghi, glo, MTOK, 768, FF_,
                                                             nullptr);
    wconvert_kernel<<<dim3(24, 96), 256, 0, stream>>>(W2 + (size_t)l * FF_ * 768, w2hi, w2lo,
                                                      FF_, 768);
    // FC2 split-K=2: both halves atomically accumulate into x (z==0 adds bias)
    gemm_mfma<EPI_ATOM, 2><<<dim3(50, 6, 2), 256, 0, stream>>>(ghi, glo, w2hi, w2lo,
                                                               b2 + l * 768, x, nullptr,
                                                               nullptr, MTOK, FF_, 768,
                                                               nullptr);
  }
  head_kernel<<<32, 256, 0, stream>>>(x, Wout, bout, out);
}